// Round 2
// baseline (1761.165 us; speedup 1.0000x reference)
//
#include <hip/hip_runtime.h>

// Problem constants
#define NPX   131072      // B*H*W = 32*64*64 pixels
#define CHN   128         // NUM_HIDDENS
#define HWN   4096        // H*W
#define EMB   64
#define NCODE 512

// ws layout (bytes)
#define WS_HIST 0         // 512 * u32
#define WS_LOSS 2048      // 1 * f32
#define WS_CC   4096      // 512 * f32
#define WS_PWT  8192      // 128*64 f32 (pre_w transposed, 32 KB)
#define WS_IDX  40960     // 131072 * i32 (512 KB)

// --- prep: transpose pre_w to [c][d]; cc[k] = ||cb[k]||^2 (numpy pairwise-8, unfused)
__global__ __launch_bounds__(512) void vq_prep(const float* __restrict__ preW,
                                               const float* __restrict__ cb,
                                               float* __restrict__ preWT,
                                               float* __restrict__ cc) {
  int t = threadIdx.x;
  for (int i = t; i < CHN * EMB; i += 512) {
    int c = i >> 6, d = i & 63;
    preWT[i] = preW[d * CHN + c];   // preW is [64][128]
  }
  if (t < NCODE) {
    const float* row = cb + t * EMB;
    float r[8];
#pragma unroll
    for (int j = 0; j < 8; ++j) r[j] = __fmul_rn(row[j], row[j]);
#pragma unroll
    for (int b = 1; b < 8; ++b)
#pragma unroll
      for (int j = 0; j < 8; ++j)
        r[j] = __fadd_rn(r[j], __fmul_rn(row[b * 8 + j], row[b * 8 + j]));
    cc[t] = __fadd_rn(__fadd_rn(__fadd_rn(r[0], r[1]), __fadd_rn(r[2], r[3])),
                      __fadd_rn(__fadd_rn(r[4], r[5]), __fadd_rn(r[6], r[7])));
  }
}

// --- main: 64 pixels/block, 4 waves. Wave s: phase1 computes z[16s:16s+16],
//     phase2 searches codes [128s, 128s+128). Numerics bit-identical to the
//     1-thread-per-pixel version (same op order, same rounding, same tie-break).
__global__ __launch_bounds__(256, 6) void vq_main(const float* __restrict__ A,
                                                  const float* __restrict__ preWT,
                                                  const float* __restrict__ preB,
                                                  const float* __restrict__ cb,
                                                  const float* __restrict__ cc,
                                                  float* __restrict__ outIdx,
                                                  int* __restrict__ wsIdx,
                                                  float* __restrict__ lossAcc,
                                                  unsigned int* __restrict__ hist) {
  __shared__ __align__(16) float zbuf[64][68];  // 68: 16B-aligned rows, de-strided banks
  __shared__ float bestv[4][64];
  __shared__ int   bestk[4][64];

  const int t = threadIdx.x;
  const int pix = t & 63, s = t >> 6;
  const int p = blockIdx.x * 64 + pix;
  const int b = p >> 12, hw = p & 4095;
  const float* Ab = A + (size_t)b * CHN * HWN + hw;

  // phase 1: z-slice d in [16s, 16s+16), c-loop sequential unfused (matches ref)
  float zs[16];
#pragma unroll
  for (int j = 0; j < 16; ++j) zs[j] = 0.f;
  const float* wBase = preWT + 16 * s;
  for (int c = 0; c < CHN; ++c) {
    float a = Ab[(size_t)c * HWN];              // coalesced across lanes (pix = lane)
    const float* w = wBase + c * EMB;           // wave-uniform -> s_load
#pragma unroll
    for (int j = 0; j < 16; ++j) zs[j] = __fadd_rn(zs[j], __fmul_rn(a, w[j]));
  }
#pragma unroll
  for (int j = 0; j < 16; ++j) zs[j] = __fadd_rn(zs[j], preB[16 * s + j]);
#pragma unroll
  for (int m = 0; m < 4; ++m)
    *(float4*)&zbuf[pix][16 * s + 4 * m] = make_float4(zs[4*m], zs[4*m+1], zs[4*m+2], zs[4*m+3]);
  __syncthreads();

  // phase 2: full z into VGPRs
  float z[64];
#pragma unroll
  for (int m = 0; m < 16; ++m) {
    float4 v = *(const float4*)&zbuf[pix][4 * m];
    z[4*m] = v.x; z[4*m+1] = v.y; z[4*m+2] = v.z; z[4*m+3] = v.w;
  }

  // zz: numpy pairwise-8 order, unfused (same bits as before)
  float r[8];
#pragma unroll
  for (int j = 0; j < 8; ++j) r[j] = __fmul_rn(z[j], z[j]);
#pragma unroll
  for (int bb = 1; bb < 8; ++bb)
#pragma unroll
    for (int j = 0; j < 8; ++j)
      r[j] = __fadd_rn(r[j], __fmul_rn(z[bb * 8 + j], z[bb * 8 + j]));
  float zz = __fadd_rn(__fadd_rn(__fadd_rn(r[0], r[1]), __fadd_rn(r[2], r[3])),
                       __fadd_rn(__fadd_rn(r[4], r[5]), __fadd_rn(r[6], r[7])));

  // search this wave's 128-code range
  float best = 3.4e38f;
  int bidx = 128 * s;
  for (int k = 128 * s; k < 128 * s + 128; ++k) {
    const float* crow = cb + (k << 6);          // wave-uniform -> s_load
    float d0 = 0.f, d1 = 0.f, d2 = 0.f, d3 = 0.f;
#pragma unroll
    for (int dd = 0; dd < 64; dd += 4) {
      d0 = fmaf(crow[dd + 0], z[dd + 0], d0);
      d1 = fmaf(crow[dd + 1], z[dd + 1], d1);
      d2 = fmaf(crow[dd + 2], z[dd + 2], d2);
      d3 = fmaf(crow[dd + 3], z[dd + 3], d3);
    }
    float dot = (d0 + d1) + (d2 + d3);
    float dist = __fadd_rn(__fadd_rn(zz, cc[k]), -2.0f * dot);
    if (dist < best) { best = dist; bidx = k; }  // strict <: first-min within range
  }
  bestv[s][pix] = best;
  bestk[s][pix] = bidx;
  __syncthreads();

  // wave 0 combines ranges in ascending order (global first-min tie-break), then epilogue
  if (s == 0) {
    float fb = bestv[0][pix]; int fk = bestk[0][pix];
#pragma unroll
    for (int ss = 1; ss < 4; ++ss) {
      float v = bestv[ss][pix];
      if (v < fb) { fb = v; fk = bestk[ss][pix]; }
    }
    // loss partial: sum (q - z)^2 ; loss = 1.25 * mean
    const float4* q4 = (const float4*)(cb + (fk << 6));
    float ls = 0.f;
#pragma unroll
    for (int i = 0; i < 16; ++i) {
      float4 q = q4[i];
      float e;
      e = __fsub_rn(q.x, z[4 * i + 0]); ls = fmaf(e, e, ls);
      e = __fsub_rn(q.y, z[4 * i + 1]); ls = fmaf(e, e, ls);
      e = __fsub_rn(q.z, z[4 * i + 2]); ls = fmaf(e, e, ls);
      e = __fsub_rn(q.w, z[4 * i + 3]); ls = fmaf(e, e, ls);
    }
#pragma unroll
    for (int off = 32; off; off >>= 1) ls += __shfl_xor(ls, off, 64);
    if (pix == 0) atomicAdd(lossAcc, ls);
    atomicAdd(&hist[fk], 1u);
    wsIdx[p] = fk;
    outIdx[p] = (float)fk;
  }
}

// --- decode: 64 pixels/block, 4 waves; wave s does o in [32s, 32s+32)
__global__ __launch_bounds__(256, 6) void vq_decode(const float* __restrict__ cb,
                                                    const int* __restrict__ wsIdx,
                                                    const float* __restrict__ postW,
                                                    const float* __restrict__ postB,
                                                    float* __restrict__ dec) {
  const int t = threadIdx.x;
  const int pix = t & 63, s = t >> 6;
  const int p = blockIdx.x * 64 + pix;
  const int b = p >> 12, hw = p & 4095;
  const int k = wsIdx[p];

  float q[64];
  const float4* q4 = (const float4*)(cb + (k << 6));
#pragma unroll
  for (int i = 0; i < 16; ++i) {
    float4 v = q4[i];
    q[4 * i + 0] = v.x; q[4 * i + 1] = v.y; q[4 * i + 2] = v.z; q[4 * i + 3] = v.w;
  }
  float* out = dec + (size_t)b * CHN * HWN + hw;
  for (int oi = 0; oi < 32; ++oi) {
    int o = 32 * s + oi;
    const float* w = postW + o * EMB;           // wave-uniform -> s_load
    float a0 = 0.f, a1 = 0.f, a2 = 0.f, a3 = 0.f;
#pragma unroll
    for (int dd = 0; dd < 64; dd += 4) {
      a0 = fmaf(q[dd + 0], w[dd + 0], a0);
      a1 = fmaf(q[dd + 1], w[dd + 1], a1);
      a2 = fmaf(q[dd + 2], w[dd + 2], a2);
      a3 = fmaf(q[dd + 3], w[dd + 3], a3);
    }
    out[(size_t)o * HWN] = ((a0 + a1) + (a2 + a3)) + postB[o];  // coalesced per o
  }
}

// --- finalize: loss scalar + perplexity
__global__ __launch_bounds__(512) void vq_final(const unsigned int* __restrict__ hist,
                                                const float* __restrict__ lossAcc,
                                                float* __restrict__ outLoss,
                                                float* __restrict__ outPerp) {
  __shared__ float sred[8];
  int t = threadIdx.x;
  float c = (float)hist[t];
  float pavg = c * (1.0f / 131072.0f);
  float term = pavg * logf(pavg + 1e-10f);
#pragma unroll
  for (int off = 32; off; off >>= 1) term += __shfl_xor(term, off, 64);
  if ((t & 63) == 0) sred[t >> 6] = term;
  __syncthreads();
  if (t == 0) {
    float s = 0.f;
    for (int i = 0; i < 8; ++i) s += sred[i];
    *outPerp = expf(-s);
    *outLoss = 1.25f * (*lossAcc) * (1.0f / 8388608.0f);
  }
}

extern "C" void kernel_launch(void* const* d_in, const int* in_sizes, int n_in,
                              void* d_out, int out_size, void* d_ws, size_t ws_size,
                              hipStream_t stream) {
  const float* A     = (const float*)d_in[0];
  const float* preW  = (const float*)d_in[1];
  const float* preB  = (const float*)d_in[2];
  const float* cb    = (const float*)d_in[3];
  const float* postW = (const float*)d_in[4];
  const float* postB = (const float*)d_in[5];
  float* out = (float*)d_out;

  char* ws = (char*)d_ws;
  unsigned int* hist = (unsigned int*)(ws + WS_HIST);
  float* lossAcc = (float*)(ws + WS_LOSS);
  float* cc      = (float*)(ws + WS_CC);
  float* preWT   = (float*)(ws + WS_PWT);
  int* wsIdx     = (int*)(ws + WS_IDX);

  hipMemsetAsync(ws, 0, 2052, stream);  // zero hist + loss accumulator
  vq_prep<<<1, 512, 0, stream>>>(preW, cb, preWT, cc);
  vq_main<<<NPX / 64, 256, 0, stream>>>(A, preWT, preB, cb, cc,
                                        out + 16777218, wsIdx, lossAcc, hist);
  vq_decode<<<NPX / 64, 256, 0, stream>>>(cb, wsIdx, postW, postB, out + 1);
  vq_final<<<1, 512, 0, stream>>>(hist, lossAcc, out, out + 16777217);
}

// Round 3
// 1185.299 us; speedup vs baseline: 1.4858x; 1.4858x over previous
//
#include <hip/hip_runtime.h>

// Problem constants
#define NPX   131072      // B*H*W = 32*64*64 pixels
#define CHN   128         // NUM_HIDDENS
#define HWN   4096        // H*W
#define EMB   64
#define NCODE 512

// ws layout (bytes)
#define WS_HIST 0         // 512 * u32
#define WS_LOSS 2048      // 1 * f32
#define WS_CC   4096      // 512 * f32
#define WS_PWT  8192      // 128*64 f32 (pre_w transposed, 32 KB)

// --- prep: transpose pre_w to [c][d]; cc[k] = ||cb[k]||^2 (numpy pairwise-8, unfused)
__global__ __launch_bounds__(256) void vq_prep(const float* __restrict__ preW,
                                               const float* __restrict__ cb,
                                               float* __restrict__ preWT,
                                               float* __restrict__ cc) {
  int g = blockIdx.x * 256 + threadIdx.x;     // 0..1023
  for (int i = g; i < CHN * EMB; i += 1024) {
    int c = i >> 6, d = i & 63;
    preWT[i] = preW[d * CHN + c];             // preW is [64][128]
  }
  if (g < NCODE) {
    const float* row = cb + g * EMB;
    float r[8];
#pragma unroll
    for (int j = 0; j < 8; ++j) r[j] = __fmul_rn(row[j], row[j]);
#pragma unroll
    for (int b = 1; b < 8; ++b)
#pragma unroll
      for (int j = 0; j < 8; ++j)
        r[j] = __fadd_rn(r[j], __fmul_rn(row[b * 8 + j], row[b * 8 + j]));
    cc[g] = __fadd_rn(__fadd_rn(__fadd_rn(r[0], r[1]), __fadd_rn(r[2], r[3])),
                      __fadd_rn(__fadd_rn(r[4], r[5]), __fadd_rn(r[6], r[7])));
  }
}

// --- main (fused): 64 pixels/block, 4 waves.
//     phase1: wave s computes z[16s:16s+16) for all 64 px (via LDS)
//     phase2: wave s searches codes [128s,128s+128) with full z in VGPRs
//     combine (wave 0, ascending ranges -> global first-min tie-break)
//     epilogue: per-wave loss slice + fused post-conv decode (wave s -> o in [32s,32s+32))
//     Numerics of z/zz/dist/argmin are op-for-op identical to the round-1 kernel.
//     launch_bounds(256,4): 128-VGPR cap, demand ~90 -> NO scratch spill (round-2 bug).
__global__ __launch_bounds__(256, 4) void vq_main(const float* __restrict__ A,
                                                  const float* __restrict__ preWT,
                                                  const float* __restrict__ preB,
                                                  const float* __restrict__ cb,
                                                  const float* __restrict__ cc,
                                                  const float* __restrict__ postW,
                                                  const float* __restrict__ postB,
                                                  float* __restrict__ outIdx,
                                                  float* __restrict__ dec,
                                                  float* __restrict__ lossAcc,
                                                  unsigned int* __restrict__ hist) {
  __shared__ __align__(16) float zbuf[64][68];
  __shared__ float bestv[4][64];
  __shared__ int   bestk[4][64];
  __shared__ int   fkbuf[64];

  const int t = threadIdx.x;
  const int pix = t & 63, s = t >> 6;
  const int p = blockIdx.x * 64 + pix;
  const int b = p >> 12, hw = p & 4095;
  const float* Ab = A + (size_t)b * CHN * HWN + hw;

  // phase 1: z-slice d in [16s, 16s+16), c-loop sequential unfused (matches np.einsum)
  float zs[16];
#pragma unroll
  for (int j = 0; j < 16; ++j) zs[j] = 0.f;
  const float* wBase = preWT + 16 * s;
  for (int c = 0; c < CHN; ++c) {
    float a = Ab[(size_t)c * HWN];            // coalesced (pix = lane)
    const float* w = wBase + c * EMB;         // wave-uniform -> s_load
#pragma unroll
    for (int j = 0; j < 16; ++j) zs[j] = __fadd_rn(zs[j], __fmul_rn(a, w[j]));
  }
#pragma unroll
  for (int j = 0; j < 16; ++j) zs[j] = __fadd_rn(zs[j], preB[16 * s + j]);
#pragma unroll
  for (int m = 0; m < 4; ++m)
    *(float4*)&zbuf[pix][16 * s + 4 * m] = make_float4(zs[4*m], zs[4*m+1], zs[4*m+2], zs[4*m+3]);
  __syncthreads();

  // phase 2: full z into VGPRs
  float z[64];
#pragma unroll
  for (int m = 0; m < 16; ++m) {
    float4 v = *(const float4*)&zbuf[pix][4 * m];
    z[4*m] = v.x; z[4*m+1] = v.y; z[4*m+2] = v.z; z[4*m+3] = v.w;
  }

  // zz: numpy pairwise-8 order, unfused
  float r[8];
#pragma unroll
  for (int j = 0; j < 8; ++j) r[j] = __fmul_rn(z[j], z[j]);
#pragma unroll
  for (int bb = 1; bb < 8; ++bb)
#pragma unroll
    for (int j = 0; j < 8; ++j)
      r[j] = __fadd_rn(r[j], __fmul_rn(z[bb * 8 + j], z[bb * 8 + j]));
  float zz = __fadd_rn(__fadd_rn(__fadd_rn(r[0], r[1]), __fadd_rn(r[2], r[3])),
                       __fadd_rn(__fadd_rn(r[4], r[5]), __fadd_rn(r[6], r[7])));

  // search this wave's 128-code range
  float best = 3.4e38f;
  int bidx = 128 * s;
  for (int k = 128 * s; k < 128 * s + 128; ++k) {
    const float* crow = cb + (k << 6);        // wave-uniform -> s_load
    float d0 = 0.f, d1 = 0.f, d2 = 0.f, d3 = 0.f;
#pragma unroll
    for (int dd = 0; dd < 64; dd += 4) {
      d0 = fmaf(crow[dd + 0], z[dd + 0], d0);
      d1 = fmaf(crow[dd + 1], z[dd + 1], d1);
      d2 = fmaf(crow[dd + 2], z[dd + 2], d2);
      d3 = fmaf(crow[dd + 3], z[dd + 3], d3);
    }
    float dot = (d0 + d1) + (d2 + d3);
    float dist = __fadd_rn(__fadd_rn(zz, cc[k]), -2.0f * dot);
    if (dist < best) { best = dist; bidx = k; }  // strict <: first-min within range
  }
  bestv[s][pix] = best;
  bestk[s][pix] = bidx;
  __syncthreads();

  // wave 0: combine ranges ascending (global first-min), publish index
  if (s == 0) {
    float fb = bestv[0][pix]; int fk = bestk[0][pix];
#pragma unroll
    for (int ss = 1; ss < 4; ++ss) {
      float v = bestv[ss][pix];
      if (v < fb) { fb = v; fk = bestk[ss][pix]; }
    }
    fkbuf[pix] = fk;
    atomicAdd(&hist[fk], 1u);
    outIdx[p] = (float)fk;
  }
  __syncthreads();
  const int fk = fkbuf[pix];
  const float4* q4 = (const float4*)(cb + (fk << 6));

  // loss slice: wave s sums (q-z)^2 over dims [16s,16s+16) (order-free tolerance)
  {
    float ls = 0.f;
#pragma unroll
    for (int i = 4 * s; i < 4 * s + 4; ++i) {
      float4 q = q4[i];
      float e;
      e = __fsub_rn(q.x, z[4 * i + 0]); ls = fmaf(e, e, ls);
      e = __fsub_rn(q.y, z[4 * i + 1]); ls = fmaf(e, e, ls);
      e = __fsub_rn(q.z, z[4 * i + 2]); ls = fmaf(e, e, ls);
      e = __fsub_rn(q.w, z[4 * i + 3]); ls = fmaf(e, e, ls);
    }
#pragma unroll
    for (int off = 32; off; off >>= 1) ls += __shfl_xor(ls, off, 64);
    if (pix == 0) atomicAdd(lossAcc, ls);
  }

  // fused decode: wave s computes o in [32s, 32s+32)
  float q[64];
#pragma unroll
  for (int i = 0; i < 16; ++i) {
    float4 v = q4[i];
    q[4 * i + 0] = v.x; q[4 * i + 1] = v.y; q[4 * i + 2] = v.z; q[4 * i + 3] = v.w;
  }
  float* out = dec + (size_t)b * CHN * HWN + hw;
  for (int oi = 0; oi < 32; ++oi) {
    int o = 32 * s + oi;
    const float* w = postW + o * EMB;          // wave-uniform -> s_load
    float a0 = 0.f, a1 = 0.f, a2 = 0.f, a3 = 0.f;
#pragma unroll
    for (int dd = 0; dd < 64; dd += 4) {
      a0 = fmaf(q[dd + 0], w[dd + 0], a0);
      a1 = fmaf(q[dd + 1], w[dd + 1], a1);
      a2 = fmaf(q[dd + 2], w[dd + 2], a2);
      a3 = fmaf(q[dd + 3], w[dd + 3], a3);
    }
    out[(size_t)o * HWN] = ((a0 + a1) + (a2 + a3)) + postB[o];  // coalesced per o
  }
}

// --- finalize: loss scalar + perplexity
__global__ __launch_bounds__(512) void vq_final(const unsigned int* __restrict__ hist,
                                                const float* __restrict__ lossAcc,
                                                float* __restrict__ outLoss,
                                                float* __restrict__ outPerp) {
  __shared__ float sred[8];
  int t = threadIdx.x;
  float c = (float)hist[t];
  float pavg = c * (1.0f / 131072.0f);
  float term = pavg * logf(pavg + 1e-10f);
#pragma unroll
  for (int off = 32; off; off >>= 1) term += __shfl_xor(term, off, 64);
  if ((t & 63) == 0) sred[t >> 6] = term;
  __syncthreads();
  if (t == 0) {
    float s = 0.f;
    for (int i = 0; i < 8; ++i) s += sred[i];
    *outPerp = expf(-s);
    *outLoss = 1.25f * (*lossAcc) * (1.0f / 8388608.0f);
  }
}

extern "C" void kernel_launch(void* const* d_in, const int* in_sizes, int n_in,
                              void* d_out, int out_size, void* d_ws, size_t ws_size,
                              hipStream_t stream) {
  const float* A     = (const float*)d_in[0];
  const float* preW  = (const float*)d_in[1];
  const float* preB  = (const float*)d_in[2];
  const float* cb    = (const float*)d_in[3];
  const float* postW = (const float*)d_in[4];
  const float* postB = (const float*)d_in[5];
  float* out = (float*)d_out;

  char* ws = (char*)d_ws;
  unsigned int* hist = (unsigned int*)(ws + WS_HIST);
  float* lossAcc = (float*)(ws + WS_LOSS);
  float* cc      = (float*)(ws + WS_CC);
  float* preWT   = (float*)(ws + WS_PWT);

  hipMemsetAsync(ws, 0, 2052, stream);  // zero hist + loss accumulator
  vq_prep<<<4, 256, 0, stream>>>(preW, cb, preWT, cc);
  vq_main<<<NPX / 64, 256, 0, stream>>>(A, preWT, preB, cb, cc, postW, postB,
                                        out + 16777218, out + 1, lossAcc, hist);
  vq_final<<<1, 512, 0, stream>>>(hist, lossAcc, out, out + 16777217);
}

// Round 4
// 1158.961 us; speedup vs baseline: 1.5196x; 1.0227x over previous
//
#include <hip/hip_runtime.h>

// Problem constants
#define NPX   131072      // B*H*W = 32*64*64 pixels
#define CHN   128         // NUM_HIDDENS
#define HWN   4096        // H*W
#define EMB   64
#define NCODE 512

// ws layout (bytes)
#define WS_HIST 0         // 512 * u32
#define WS_LOSS 2048      // 4 * f32 (per-wave-slice loss accumulators)
#define WS_CC   4096      // 512 * f32
#define WS_PWT  8192      // 128*64 f32 (pre_w transposed, 32 KB)

// --- prep: transpose pre_w to [c][d]; cc[k] = ||cb[k]||^2 (numpy pairwise-8, unfused)
__global__ __launch_bounds__(256) void vq_prep(const float* __restrict__ preW,
                                               const float* __restrict__ cb,
                                               float* __restrict__ preWT,
                                               float* __restrict__ cc) {
  int g = blockIdx.x * 256 + threadIdx.x;     // 0..1023
  for (int i = g; i < CHN * EMB; i += 1024) {
    int c = i >> 6, d = i & 63;
    preWT[i] = preW[d * CHN + c];             // preW is [64][128]
  }
  if (g < NCODE) {
    const float* row = cb + g * EMB;
    float r[8];
#pragma unroll
    for (int j = 0; j < 8; ++j) r[j] = __fmul_rn(row[j], row[j]);
#pragma unroll
    for (int b = 1; b < 8; ++b)
#pragma unroll
      for (int j = 0; j < 8; ++j)
        r[j] = __fadd_rn(r[j], __fmul_rn(row[b * 8 + j], row[b * 8 + j]));
    cc[g] = __fadd_rn(__fadd_rn(__fadd_rn(r[0], r[1]), __fadd_rn(r[2], r[3])),
                      __fadd_rn(__fadd_rn(r[4], r[5]), __fadd_rn(r[6], r[7])));
  }
}

// --- main (fused): 64 pixels/block, 4 waves, k-range split.
//     REGISTER DISCIPLINE (the r2/r3 failures were scratch spill):
//       phase2 holds z[64] (~85 live); z DIES at end of search.
//       loss reads the z-slice from zbuf (LDS) — never re-materializes z.
//       decode then holds q[64] (~80 live). Max-live stays < 100 < 128 cap.
__global__ __launch_bounds__(256, 4) void vq_main(const float* __restrict__ A,
                                                  const float* __restrict__ preWT,
                                                  const float* __restrict__ preB,
                                                  const float* __restrict__ cb,
                                                  const float* __restrict__ cc,
                                                  const float* __restrict__ postW,
                                                  const float* __restrict__ postB,
                                                  float* __restrict__ outIdx,
                                                  float* __restrict__ dec,
                                                  float* __restrict__ lossAcc,
                                                  unsigned int* __restrict__ hist) {
  __shared__ __align__(16) float zbuf[64][68];  // 64-float rows + 4 pad (break 16-way banks)
  __shared__ float bestv[4][64];
  __shared__ int   bestk[4][64];
  __shared__ int   fkbuf[64];

  const int t = threadIdx.x;
  const int pix = t & 63, s = t >> 6;
  const int p = blockIdx.x * 64 + pix;
  const int b = p >> 12, hw = p & 4095;
  const float* Ab = A + (size_t)b * CHN * HWN + hw;

  // ---- phase 1: z-slice d in [16s,16s+16), c sequential unfused (matches np.einsum)
  {
    float zs[16];
#pragma unroll
    for (int j = 0; j < 16; ++j) zs[j] = 0.f;
    const float* wBase = preWT + 16 * s;
    for (int c = 0; c < CHN; ++c) {
      float a = Ab[(size_t)c * HWN];            // coalesced (pix = lane)
      const float* w = wBase + c * EMB;         // wave-uniform -> s_load
#pragma unroll
      for (int j = 0; j < 16; ++j) zs[j] = __fadd_rn(zs[j], __fmul_rn(a, w[j]));
    }
#pragma unroll
    for (int j = 0; j < 16; ++j) zs[j] = __fadd_rn(zs[j], preB[16 * s + j]);
#pragma unroll
    for (int m = 0; m < 4; ++m)
      *(float4*)&zbuf[pix][16 * s + 4 * m] =
          make_float4(zs[4*m], zs[4*m+1], zs[4*m+2], zs[4*m+3]);
  }
  __syncthreads();

  // ---- phase 2: full z in VGPRs, search codes [128s, 128s+128)
  {
    float z[64];
#pragma unroll
    for (int m = 0; m < 16; ++m) {
      float4 v = *(const float4*)&zbuf[pix][4 * m];
      z[4*m] = v.x; z[4*m+1] = v.y; z[4*m+2] = v.z; z[4*m+3] = v.w;
    }
    // zz: numpy pairwise-8 order, unfused
    float r[8];
#pragma unroll
    for (int j = 0; j < 8; ++j) r[j] = __fmul_rn(z[j], z[j]);
#pragma unroll
    for (int bb = 1; bb < 8; ++bb)
#pragma unroll
      for (int j = 0; j < 8; ++j)
        r[j] = __fadd_rn(r[j], __fmul_rn(z[bb * 8 + j], z[bb * 8 + j]));
    float zz = __fadd_rn(__fadd_rn(__fadd_rn(r[0], r[1]), __fadd_rn(r[2], r[3])),
                         __fadd_rn(__fadd_rn(r[4], r[5]), __fadd_rn(r[6], r[7])));

    float best = 3.4e38f;
    int bidx = 128 * s;
    for (int k = 128 * s; k < 128 * s + 128; ++k) {
      const float* crow = cb + (k << 6);        // wave-uniform -> s_load
      float d0 = 0.f, d1 = 0.f, d2 = 0.f, d3 = 0.f;
#pragma unroll
      for (int dd = 0; dd < 64; dd += 4) {
        d0 = fmaf(crow[dd + 0], z[dd + 0], d0);
        d1 = fmaf(crow[dd + 1], z[dd + 1], d1);
        d2 = fmaf(crow[dd + 2], z[dd + 2], d2);
        d3 = fmaf(crow[dd + 3], z[dd + 3], d3);
      }
      float dot = (d0 + d1) + (d2 + d3);
      float tt = __fadd_rn(zz, cc[k]);
      float dist = fmaf(-2.0f, dot, tt);        // == fl(tt - 2*dot): 2*dot exact
      if (dist < best) { best = dist; bidx = k; }  // strict <: first-min in range
    }
    bestv[s][pix] = best;
    bestk[s][pix] = bidx;
  }  // z dead here
  __syncthreads();

  // ---- combine (wave 0, ascending ranges -> global first-min tie-break)
  if (s == 0) {
    float fb = bestv[0][pix]; int fk = bestk[0][pix];
#pragma unroll
    for (int ss = 1; ss < 4; ++ss) {
      float v = bestv[ss][pix];
      if (v < fb) { fb = v; fk = bestk[ss][pix]; }
    }
    fkbuf[pix] = fk;
    atomicAdd(&hist[fk], 1u);
    outIdx[p] = (float)fk;
  }
  __syncthreads();
  const int fk = fkbuf[pix];
  const float4* q4 = (const float4*)(cb + (fk << 6));

  // ---- loss slice: wave s sums (q-z)^2 over dims [16s,16s+16), z from LDS
  {
    float ls = 0.f;
#pragma unroll
    for (int m = 0; m < 4; ++m) {
      float4 q = q4[4 * s + m];
      float4 zv = *(const float4*)&zbuf[pix][16 * s + 4 * m];
      float e;
      e = __fsub_rn(q.x, zv.x); ls = fmaf(e, e, ls);
      e = __fsub_rn(q.y, zv.y); ls = fmaf(e, e, ls);
      e = __fsub_rn(q.z, zv.z); ls = fmaf(e, e, ls);
      e = __fsub_rn(q.w, zv.w); ls = fmaf(e, e, ls);
    }
#pragma unroll
    for (int off = 32; off; off >>= 1) ls += __shfl_xor(ls, off, 64);
    if (pix == 0) atomicAdd(&lossAcc[s], ls);   // 4 accumulators: no extra contention
  }

  // ---- fused decode: wave s computes o in [32s, 32s+32); only q[64] live
  {
    float q[64];
#pragma unroll
    for (int i = 0; i < 16; ++i) {
      float4 v = q4[i];
      q[4*i+0] = v.x; q[4*i+1] = v.y; q[4*i+2] = v.z; q[4*i+3] = v.w;
    }
    float* out = dec + (size_t)b * CHN * HWN + hw;
    for (int oi = 0; oi < 32; ++oi) {
      int o = 32 * s + oi;
      const float* w = postW + o * EMB;          // wave-uniform -> s_load
      float a0 = 0.f, a1 = 0.f, a2 = 0.f, a3 = 0.f;
#pragma unroll
      for (int dd = 0; dd < 64; dd += 4) {
        a0 = fmaf(q[dd + 0], w[dd + 0], a0);
        a1 = fmaf(q[dd + 1], w[dd + 1], a1);
        a2 = fmaf(q[dd + 2], w[dd + 2], a2);
        a3 = fmaf(q[dd + 3], w[dd + 3], a3);
      }
      out[(size_t)o * HWN] = ((a0 + a1) + (a2 + a3)) + postB[o];  // coalesced per o
    }
  }
}

// --- finalize: loss scalar + perplexity
__global__ __launch_bounds__(512) void vq_final(const unsigned int* __restrict__ hist,
                                                const float* __restrict__ lossAcc,
                                                float* __restrict__ outLoss,
                                                float* __restrict__ outPerp) {
  __shared__ float sred[8];
  int t = threadIdx.x;
  float c = (float)hist[t];
  float pavg = c * (1.0f / 131072.0f);
  float term = pavg * logf(pavg + 1e-10f);
#pragma unroll
  for (int off = 32; off; off >>= 1) term += __shfl_xor(term, off, 64);
  if ((t & 63) == 0) sred[t >> 6] = term;
  __syncthreads();
  if (t == 0) {
    float sum = 0.f;
    for (int i = 0; i < 8; ++i) sum += sred[i];
    *outPerp = expf(-sum);
    float l = ((lossAcc[0] + lossAcc[1]) + (lossAcc[2] + lossAcc[3]));
    *outLoss = 1.25f * l * (1.0f / 8388608.0f);
  }
}

extern "C" void kernel_launch(void* const* d_in, const int* in_sizes, int n_in,
                              void* d_out, int out_size, void* d_ws, size_t ws_size,
                              hipStream_t stream) {
  const float* A     = (const float*)d_in[0];
  const float* preW  = (const float*)d_in[1];
  const float* preB  = (const float*)d_in[2];
  const float* cb    = (const float*)d_in[3];
  const float* postW = (const float*)d_in[4];
  const float* postB = (const float*)d_in[5];
  float* out = (float*)d_out;

  char* ws = (char*)d_ws;
  unsigned int* hist = (unsigned int*)(ws + WS_HIST);
  float* lossAcc = (float*)(ws + WS_LOSS);
  float* cc      = (float*)(ws + WS_CC);
  float* preWT   = (float*)(ws + WS_PWT);

  hipMemsetAsync(ws, 0, 2064, stream);  // zero hist + 4 loss accumulators
  vq_prep<<<4, 256, 0, stream>>>(preW, cb, preWT, cc);
  vq_main<<<NPX / 64, 256, 0, stream>>>(A, preWT, preB, cb, cc, postW, postB,
                                        out + 16777218, out + 1, lossAcc, hist);
  vq_final<<<1, 512, 0, stream>>>(hist, lossAcc, out, out + 16777217);
}

// Round 5
// 851.795 us; speedup vs baseline: 2.0676x; 1.3606x over previous
//
#include <hip/hip_runtime.h>

// Problem constants
#define NPX   131072      // B*H*W = 32*64*64 pixels
#define CHN   128         // NUM_HIDDENS
#define HWN   4096        // H*W
#define EMB   64
#define NCODE 512

// ws layout (bytes)
#define WS_HIST 0         // 512 * u32
#define WS_LOSS 2048      // 4 * f32 (per-wave-slice loss accumulators)
#define WS_CC   4096      // 512 * f32
#define WS_PWT  8192      // 128*64 f32 (pre_w transposed, 32 KB)

// --- prep: transpose pre_w to [c][d]; cc[k] = ||cb[k]||^2 (numpy pairwise-8, unfused)
__global__ __launch_bounds__(256) void vq_prep(const float* __restrict__ preW,
                                               const float* __restrict__ cb,
                                               float* __restrict__ preWT,
                                               float* __restrict__ cc) {
  int g = blockIdx.x * 256 + threadIdx.x;     // 0..1023
  for (int i = g; i < CHN * EMB; i += 1024) {
    int c = i >> 6, d = i & 63;
    preWT[i] = preW[d * CHN + c];             // preW is [64][128]
  }
  if (g < NCODE) {
    const float* row = cb + g * EMB;
    float r[8];
#pragma unroll
    for (int j = 0; j < 8; ++j) r[j] = __fmul_rn(row[j], row[j]);
#pragma unroll
    for (int b = 1; b < 8; ++b)
#pragma unroll
      for (int j = 0; j < 8; ++j)
        r[j] = __fadd_rn(r[j], __fmul_rn(row[b * 8 + j], row[b * 8 + j]));
    cc[g] = __fadd_rn(__fadd_rn(__fadd_rn(r[0], r[1]), __fadd_rn(r[2], r[3])),
                      __fadd_rn(__fadd_rn(r[4], r[5]), __fadd_rn(r[6], r[7])));
  }
}

// --- main (fused): 64 pixels/block, 4 waves, k-range split.
//     NO register cap: r2(cap85)/r3/r4(cap128) all spilled z to scratch
//     (FETCH 0.6-0.9 GB); r1 (no cap) allocated 44 VGPR + 96 SGPR, zero spill
//     (codebook rows via s_load -> SGPR operands on v_fma). Let the allocator
//     reproduce that regime; occupancy comes from the 8192-wave grid.
__global__ __launch_bounds__(256) void vq_main(const float* __restrict__ A,
                                               const float* __restrict__ preWT,
                                               const float* __restrict__ preB,
                                               const float* __restrict__ cb,
                                               const float* __restrict__ cc,
                                               const float* __restrict__ postW,
                                               const float* __restrict__ postB,
                                               float* __restrict__ outIdx,
                                               float* __restrict__ dec,
                                               float* __restrict__ lossAcc,
                                               unsigned int* __restrict__ hist) {
  __shared__ __align__(16) float zbuf[64][68];  // 64-float rows + 4 pad
  __shared__ float bestv[4][64];
  __shared__ int   bestk[4][64];
  __shared__ int   fkbuf[64];

  const int t = threadIdx.x;
  const int pix = t & 63, s = t >> 6;
  const int p = blockIdx.x * 64 + pix;
  const int b = p >> 12, hw = p & 4095;
  const float* Ab = A + (size_t)b * CHN * HWN + hw;

  // ---- phase 1: z-slice d in [16s,16s+16), c sequential unfused (matches np.einsum)
  {
    float zs[16];
#pragma unroll
    for (int j = 0; j < 16; ++j) zs[j] = 0.f;
    const float* wBase = preWT + 16 * s;
    for (int c = 0; c < CHN; ++c) {
      float a = Ab[(size_t)c * HWN];            // coalesced (pix = lane)
      const float* w = wBase + c * EMB;         // wave-uniform -> s_load
#pragma unroll
      for (int j = 0; j < 16; ++j) zs[j] = __fadd_rn(zs[j], __fmul_rn(a, w[j]));
    }
#pragma unroll
    for (int j = 0; j < 16; ++j) zs[j] = __fadd_rn(zs[j], preB[16 * s + j]);
#pragma unroll
    for (int m = 0; m < 4; ++m)
      *(float4*)&zbuf[pix][16 * s + 4 * m] =
          make_float4(zs[4*m], zs[4*m+1], zs[4*m+2], zs[4*m+3]);
  }
  __syncthreads();

  // ---- phase 2: full z in VGPRs, search codes [128s, 128s+128)
  {
    float z[64];
#pragma unroll
    for (int m = 0; m < 16; ++m) {
      float4 v = *(const float4*)&zbuf[pix][4 * m];
      z[4*m] = v.x; z[4*m+1] = v.y; z[4*m+2] = v.z; z[4*m+3] = v.w;
    }
    // zz: numpy pairwise-8 order, unfused
    float r[8];
#pragma unroll
    for (int j = 0; j < 8; ++j) r[j] = __fmul_rn(z[j], z[j]);
#pragma unroll
    for (int bb = 1; bb < 8; ++bb)
#pragma unroll
      for (int j = 0; j < 8; ++j)
        r[j] = __fadd_rn(r[j], __fmul_rn(z[bb * 8 + j], z[bb * 8 + j]));
    float zz = __fadd_rn(__fadd_rn(__fadd_rn(r[0], r[1]), __fadd_rn(r[2], r[3])),
                         __fadd_rn(__fadd_rn(r[4], r[5]), __fadd_rn(r[6], r[7])));

    float best = 3.4e38f;
    int bidx = 128 * s;
    for (int k = 128 * s; k < 128 * s + 128; ++k) {
      const float* crow = cb + (k << 6);        // wave-uniform -> s_load
      float d0 = 0.f, d1 = 0.f, d2 = 0.f, d3 = 0.f;
#pragma unroll
      for (int dd = 0; dd < 64; dd += 4) {
        d0 = fmaf(crow[dd + 0], z[dd + 0], d0);
        d1 = fmaf(crow[dd + 1], z[dd + 1], d1);
        d2 = fmaf(crow[dd + 2], z[dd + 2], d2);
        d3 = fmaf(crow[dd + 3], z[dd + 3], d3);
      }
      float dot = (d0 + d1) + (d2 + d3);
      float tt = __fadd_rn(zz, cc[k]);
      float dist = fmaf(-2.0f, dot, tt);        // == fl(tt - 2*dot): 2*dot exact
      if (dist < best) { best = dist; bidx = k; }  // strict <: first-min in range
    }
    bestv[s][pix] = best;
    bestk[s][pix] = bidx;
  }  // z dead here
  __syncthreads();

  // ---- combine (wave 0, ascending ranges -> global first-min tie-break)
  if (s == 0) {
    float fb = bestv[0][pix]; int fk = bestk[0][pix];
#pragma unroll
    for (int ss = 1; ss < 4; ++ss) {
      float v = bestv[ss][pix];
      if (v < fb) { fb = v; fk = bestk[ss][pix]; }
    }
    fkbuf[pix] = fk;
    atomicAdd(&hist[fk], 1u);
    outIdx[p] = (float)fk;
  }
  __syncthreads();
  const int fk = fkbuf[pix];
  const float4* q4 = (const float4*)(cb + (fk << 6));

  // ---- loss slice: wave s sums (q-z)^2 over dims [16s,16s+16), z from LDS
  {
    float ls = 0.f;
#pragma unroll
    for (int m = 0; m < 4; ++m) {
      float4 q = q4[4 * s + m];
      float4 zv = *(const float4*)&zbuf[pix][16 * s + 4 * m];
      float e;
      e = __fsub_rn(q.x, zv.x); ls = fmaf(e, e, ls);
      e = __fsub_rn(q.y, zv.y); ls = fmaf(e, e, ls);
      e = __fsub_rn(q.z, zv.z); ls = fmaf(e, e, ls);
      e = __fsub_rn(q.w, zv.w); ls = fmaf(e, e, ls);
    }
#pragma unroll
    for (int off = 32; off; off >>= 1) ls += __shfl_xor(ls, off, 64);
    if (pix == 0) atomicAdd(&lossAcc[s], ls);
  }

  // ---- fused decode: wave s computes o in [32s, 32s+32); only q[64] live
  {
    float q[64];
#pragma unroll
    for (int i = 0; i < 16; ++i) {
      float4 v = q4[i];
      q[4*i+0] = v.x; q[4*i+1] = v.y; q[4*i+2] = v.z; q[4*i+3] = v.w;
    }
    float* out = dec + (size_t)b * CHN * HWN + hw;
    for (int oi = 0; oi < 32; ++oi) {
      int o = 32 * s + oi;
      const float* w = postW + o * EMB;          // wave-uniform -> s_load
      float a0 = 0.f, a1 = 0.f, a2 = 0.f, a3 = 0.f;
#pragma unroll
      for (int dd = 0; dd < 64; dd += 4) {
        a0 = fmaf(q[dd + 0], w[dd + 0], a0);
        a1 = fmaf(q[dd + 1], w[dd + 1], a1);
        a2 = fmaf(q[dd + 2], w[dd + 2], a2);
        a3 = fmaf(q[dd + 3], w[dd + 3], a3);
      }
      out[(size_t)o * HWN] = ((a0 + a1) + (a2 + a3)) + postB[o];  // coalesced per o
    }
  }
}

// --- finalize: loss scalar + perplexity
__global__ __launch_bounds__(512) void vq_final(const unsigned int* __restrict__ hist,
                                                const float* __restrict__ lossAcc,
                                                float* __restrict__ outLoss,
                                                float* __restrict__ outPerp) {
  __shared__ float sred[8];
  int t = threadIdx.x;
  float c = (float)hist[t];
  float pavg = c * (1.0f / 131072.0f);
  float term = pavg * logf(pavg + 1e-10f);
#pragma unroll
  for (int off = 32; off; off >>= 1) term += __shfl_xor(term, off, 64);
  if ((t & 63) == 0) sred[t >> 6] = term;
  __syncthreads();
  if (t == 0) {
    float sum = 0.f;
    for (int i = 0; i < 8; ++i) sum += sred[i];
    *outPerp = expf(-sum);
    float l = ((lossAcc[0] + lossAcc[1]) + (lossAcc[2] + lossAcc[3]));
    *outLoss = 1.25f * l * (1.0f / 8388608.0f);
  }
}

extern "C" void kernel_launch(void* const* d_in, const int* in_sizes, int n_in,
                              void* d_out, int out_size, void* d_ws, size_t ws_size,
                              hipStream_t stream) {
  const float* A     = (const float*)d_in[0];
  const float* preW  = (const float*)d_in[1];
  const float* preB  = (const float*)d_in[2];
  const float* cb    = (const float*)d_in[3];
  const float* postW = (const float*)d_in[4];
  const float* postB = (const float*)d_in[5];
  float* out = (float*)d_out;

  char* ws = (char*)d_ws;
  unsigned int* hist = (unsigned int*)(ws + WS_HIST);
  float* lossAcc = (float*)(ws + WS_LOSS);
  float* cc      = (float*)(ws + WS_CC);
  float* preWT   = (float*)(ws + WS_PWT);

  hipMemsetAsync(ws, 0, 2064, stream);  // zero hist + 4 loss accumulators
  vq_prep<<<4, 256, 0, stream>>>(preW, cb, preWT, cc);
  vq_main<<<NPX / 64, 256, 0, stream>>>(A, preWT, preB, cb, cc, postW, postB,
                                        out + 16777218, out + 1, lossAcc, hist);
  vq_final<<<1, 512, 0, stream>>>(hist, lossAcc, out, out + 16777217);
}